// Round 6
// baseline (31.953 us; speedup 1.0000x reference)
//
#include <hip/hip_runtime.h>

// RoI crop-and-resize pooling.
// feature_map: (8, 64, 64, 256) f32 NHWC
// roi_bboxes:  (8, 300, 4) f32  (y_lo, x_lo, y_hi, x_hi), coords in [0,1]
// out:         (8, 300, 7, 7, 256) f32
//
// R3: XCD swizzle + NT stores -> 33.6us.  R4: 2 out/thr -> 30.7us.
// R5: 4 out/thr -> 30.1us (neutral; ILP lever exhausted).
// R6: wave-uniform pixel addressing. One pixel = 256 f32 = 64 lanes x f32x4,
//     so each wave owns 4 whole pixels; every gather instruction is
//     uniform-base + lane*16B = one contiguous 1KiB stream (no address
//     divergence), and all coord/index math is wave-uniform -> SALU/SGPR
//     (forced via readfirstlane on the wave id). Keeps 16 loads in flight.

typedef float f32x4 __attribute__((ext_vector_type(4)));

constexpr int B  = 8;
constexpr int N  = 300;
constexpr int H  = 64;
constexpr int W  = 64;
constexpr int C  = 256;
constexpr int C4 = C / 4;            // 64 float4 per pixel = one wave-load
constexpr int PH = 7;
constexpr int PW = 7;
constexpr int NPIX   = B * N * PH * PW;       // 117,600 pixels
constexpr int PIX_PER_WAVE  = 4;
constexpr int PIX_PER_BLOCK = 16;             // 4 waves
constexpr int NBLK   = NPIX / PIX_PER_BLOCK;  // 7,350
constexpr int NXCD   = 8;
constexpr int SWZ_Q  = NBLK / NXCD;           // 918
constexpr int SWZ_R  = NBLK % NXCD;           // 6

__global__ __launch_bounds__(256) void roipool_kernel(
    const float* __restrict__ fm,
    const float* __restrict__ boxes,
    float* __restrict__ out)
{
    // Bijective chunked XCD swizzle (general q/r form since NBLK % 8 != 0).
    int bid  = blockIdx.x;
    int xcd  = bid & (NXCD - 1);
    int base = (xcd < SWZ_R) ? xcd * (SWZ_Q + 1)
                             : SWZ_R * (SWZ_Q + 1) + (xcd - SWZ_R) * SWZ_Q;
    int swz  = base + (bid >> 3);

    int tid  = (int)threadIdx.x;
    // wave id is uniform across the wave; make it explicit so ALL downstream
    // pixel math lands in SGPRs / SALU.
    int wave = __builtin_amdgcn_readfirstlane(tid >> 6);   // 0..3
    int lane = tid & 63;                                    // f32x4 slot in pixel

    int pix0 = swz * PIX_PER_BLOCK + wave * PIX_PER_WAVE;   // uniform

    const f32x4* f  = reinterpret_cast<const f32x4*>(fm);
    f32x4*       o  = reinterpret_cast<f32x4*>(out);
    const f32x4* bb = reinterpret_cast<const f32x4*>(boxes);

    int   a_tl[PIX_PER_WAVE], a_tr[PIX_PER_WAVE], a_bl[PIX_PER_WAVE], a_br[PIX_PER_WAVE];
    float wxx[PIX_PER_WAVE], wyy[PIX_PER_WAVE];
    bool  vld[PIX_PER_WAVE];

    #pragma unroll
    for (int i = 0; i < PIX_PER_WAVE; ++i) {
        int pix  = pix0 + i;                 // uniform
        int pw   = pix % PW;
        int t2   = pix / PW;
        int ph   = t2 % PH;
        int box  = t2 / PH;                  // b*N + n
        int bimg = box / N;

        f32x4 bx = bb[box];                  // uniform address -> scalar load
        float ty = (float)ph / 6.0f;
        float tx = (float)pw / 6.0f;
        float y  = (bx.x + ty * (bx.z - bx.x)) * (float)(H - 1);
        float x  = (bx.y + tx * (bx.w - bx.y)) * (float)(W - 1);

        vld[i] = (y >= 0.0f) && (y <= (float)(H - 1)) &&
                 (x >= 0.0f) && (x <= (float)(W - 1));

        float y0f = floorf(y), x0f = floorf(x);
        wyy[i] = y - y0f;
        wxx[i] = x - x0f;

        int y0 = (int)fminf(fmaxf(y0f,        0.0f), (float)(H - 1));
        int y1 = (int)fminf(fmaxf(y0f + 1.0f, 0.0f), (float)(H - 1));
        int x0 = (int)fminf(fmaxf(x0f,        0.0f), (float)(W - 1));
        int x1 = (int)fminf(fmaxf(x0f + 1.0f, 0.0f), (float)(W - 1));

        a_tl[i] = ((bimg * H + y0) * W + x0) * C4 + lane;
        a_tr[i] = ((bimg * H + y0) * W + x1) * C4 + lane;
        a_bl[i] = ((bimg * H + y1) * W + x0) * C4 + lane;
        a_br[i] = ((bimg * H + y1) * W + x1) * C4 + lane;
    }

    // Issue all 16 gathers before any blend (max loads in flight). Each is a
    // single contiguous 1KiB wave-load.
    f32x4 tl[PIX_PER_WAVE], tr[PIX_PER_WAVE], bl[PIX_PER_WAVE], br[PIX_PER_WAVE];
    #pragma unroll
    for (int i = 0; i < PIX_PER_WAVE; ++i) {
        tl[i] = f[a_tl[i]];
        tr[i] = f[a_tr[i]];
        bl[i] = f[a_bl[i]];
        br[i] = f[a_br[i]];
    }

    #pragma unroll
    for (int i = 0; i < PIX_PER_WAVE; ++i) {
        f32x4 top = tl[i] + (tr[i] - tl[i]) * wxx[i];
        f32x4 bot = bl[i] + (br[i] - bl[i]) * wxx[i];
        f32x4 v   = top + (bot - top) * wyy[i];
        if (!vld[i]) v = (f32x4)0.0f;
        __builtin_nontemporal_store(v, o + (pix0 + i) * C4 + lane);
    }
}

extern "C" void kernel_launch(void* const* d_in, const int* in_sizes, int n_in,
                              void* d_out, int out_size, void* d_ws, size_t ws_size,
                              hipStream_t stream) {
    const float* fm    = (const float*)d_in[0];
    const float* boxes = (const float*)d_in[1];
    float* out         = (float*)d_out;

    roipool_kernel<<<NBLK, 256, 0, stream>>>(fm, boxes, out);
}

// Round 7
// 30.108 us; speedup vs baseline: 1.0613x; 1.0613x over previous
//
#include <hip/hip_runtime.h>

// RoI crop-and-resize pooling.
// feature_map: (8, 64, 64, 256) f32 NHWC
// roi_bboxes:  (8, 300, 4) f32  (y_lo, x_lo, y_hi, x_hi), coords in [0,1]
// out:         (8, 300, 7, 7, 256) f32
//
// R3: XCD swizzle + NT stores -> 33.6us.  R4: 2 out/thr -> 30.7us.
// R5: 4 out/thr -> 30.1us.  R6: wave-uniform addressing -> 32.0us (reverted).
// R7: R5 structure, but 12 pixels/block (192 thr) so blocks/image = 1225 and
//     NBLK = 9800 is divisible by 8: each XCD's contiguous chunk is EXACTLY
//     one image -> per-XCD L2 working set is one 4.2MB slice, never two.

typedef float f32x4 __attribute__((ext_vector_type(4)));

constexpr int B  = 8;
constexpr int N  = 300;
constexpr int H  = 64;
constexpr int W  = 64;
constexpr int C  = 256;
constexpr int C4 = C / 4;            // 64 float4 per pixel
constexpr int PH = 7;
constexpr int PW = 7;
constexpr int NPIX = B * N * PH * PW;         // 117,600 pixels
constexpr int PIX_PER_BLOCK = 12;             // 192 threads, 4 out/thread
constexpr int NTHR = PIX_PER_BLOCK * 16;      // 192
constexpr int NBLK = NPIX / PIX_PER_BLOCK;    // 9,800
constexpr int NXCD = 8;
constexpr int CPX  = NBLK / NXCD;             // 1,225 = exactly one image

__global__ __launch_bounds__(NTHR) void roipool_kernel(
    const float* __restrict__ fm,
    const float* __restrict__ boxes,
    float* __restrict__ out)
{
    // Bijective chunked XCD swizzle (NBLK % 8 == 0): xcd = bid % 8 gets
    // blocks [xcd*1225, (xcd+1)*1225) = exactly image xcd.
    int bid = blockIdx.x;
    int swz = (bid & (NXCD - 1)) * CPX + (bid >> 3);

    int tid = (int)threadIdx.x;
    int p   = tid >> 4;             // pixel within block, 0..11
    int c   = tid & 15;             // f32x4 lane within pixel quarter, 0..15

    int pix  = swz * PIX_PER_BLOCK + p;  // box*49 + ph*7 + pw
    int pw   = pix % PW;
    int t2   = pix / PW;
    int ph   = t2 % PH;
    int box  = t2 / PH;             // b*N + n
    int bimg = box / N;

    const f32x4 bx = reinterpret_cast<const f32x4*>(boxes)[box];
    // bx = (y_lo, x_lo, y_hi, x_hi)

    float ty = (float)ph / 6.0f;
    float tx = (float)pw / 6.0f;
    float y  = (bx.x + ty * (bx.z - bx.x)) * (float)(H - 1);
    float x  = (bx.y + tx * (bx.w - bx.y)) * (float)(W - 1);

    bool valid = (y >= 0.0f) && (y <= (float)(H - 1)) &&
                 (x >= 0.0f) && (x <= (float)(W - 1));

    float y0f = floorf(y), x0f = floorf(x);
    float wy = y - y0f;
    float wx = x - x0f;

    int y0 = (int)fminf(fmaxf(y0f,        0.0f), (float)(H - 1));
    int y1 = (int)fminf(fmaxf(y0f + 1.0f, 0.0f), (float)(H - 1));
    int x0 = (int)fminf(fmaxf(x0f,        0.0f), (float)(W - 1));
    int x1 = (int)fminf(fmaxf(x0f + 1.0f, 0.0f), (float)(W - 1));

    const f32x4* f = reinterpret_cast<const f32x4*>(fm);
    int btl = ((bimg * H + y0) * W + x0) * C4 + c;
    int btr = ((bimg * H + y0) * W + x1) * C4 + c;
    int bbl = ((bimg * H + y1) * W + x0) * C4 + c;
    int bbr = ((bimg * H + y1) * W + x1) * C4 + c;

    // 16 independent gathers (4 c4 positions x 4 corners)
    f32x4 tl0 = f[btl];      f32x4 tr0 = f[btr];
    f32x4 bl0 = f[bbl];      f32x4 br0 = f[bbr];
    f32x4 tl1 = f[btl + 16]; f32x4 tr1 = f[btr + 16];
    f32x4 bl1 = f[bbl + 16]; f32x4 br1 = f[bbr + 16];
    f32x4 tl2 = f[btl + 32]; f32x4 tr2 = f[btr + 32];
    f32x4 bl2 = f[bbl + 32]; f32x4 br2 = f[bbr + 32];
    f32x4 tl3 = f[btl + 48]; f32x4 tr3 = f[btr + 48];
    f32x4 bl3 = f[bbl + 48]; f32x4 br3 = f[bbr + 48];

    f32x4 top, bot, v0, v1, v2, v3;
    top = tl0 + (tr0 - tl0) * wx;  bot = bl0 + (br0 - bl0) * wx;
    v0  = top + (bot - top) * wy;
    top = tl1 + (tr1 - tl1) * wx;  bot = bl1 + (br1 - bl1) * wx;
    v1  = top + (bot - top) * wy;
    top = tl2 + (tr2 - tl2) * wx;  bot = bl2 + (br2 - bl2) * wx;
    v2  = top + (bot - top) * wy;
    top = tl3 + (tr3 - tl3) * wx;  bot = bl3 + (br3 - bl3) * wx;
    v3  = top + (bot - top) * wy;

    if (!valid) {
        v0 = (f32x4)0.0f; v1 = (f32x4)0.0f;
        v2 = (f32x4)0.0f; v3 = (f32x4)0.0f;
    }

    f32x4* o = reinterpret_cast<f32x4*>(out) + pix * C4 + c;
    __builtin_nontemporal_store(v0, o);
    __builtin_nontemporal_store(v1, o + 16);
    __builtin_nontemporal_store(v2, o + 32);
    __builtin_nontemporal_store(v3, o + 48);
}

extern "C" void kernel_launch(void* const* d_in, const int* in_sizes, int n_in,
                              void* d_out, int out_size, void* d_ws, size_t ws_size,
                              hipStream_t stream) {
    const float* fm    = (const float*)d_in[0];
    const float* boxes = (const float*)d_in[1];
    float* out         = (float*)d_out;

    roipool_kernel<<<NBLK, NTHR, 0, stream>>>(fm, boxes, out);
}